// Round 1
// baseline (209.323 us; speedup 1.0000x reference)
//
#include <hip/hip_runtime.h>
#include <math.h>

#define SEQ    2048
#define EMBD   50
#define L1OUT  2054     // (2048+12) - 7 + 1
#define NCHUNK 5
#define CH     512
#define RWS    520      // staged rows per chunk (CH+6 padded)
#define PITCH  64       // floats per LDS row (16 float4 slots)
#define NSLOT  13       // used float4 slots (50 floats -> 12 full + 1 half)

// ---------------- prep: Wm = mean_c W1 into ws[0..350), zeros at [350..352) --
__global__ void __launch_bounds__(384)
prep_kernel(const float* __restrict__ W1, float* __restrict__ ws) {
    int t = threadIdx.x;
    if (t < 350) {
        float s = 0.f;
        #pragma unroll
        for (int c = 0; c < 6; ++c) s += W1[t * 6 + c];
        ws[t] = s * (1.0f / 6.0f);
    } else if (t < 352) {
        ws[t] = 0.f;
    }
}

// ---------------- main: one block per batch ---------------------------------
__global__ void __launch_bounds__(256, 1)
dcnn_main(const int* __restrict__ x, const float* __restrict__ emb,
          const float* __restrict__ W1, const float* __restrict__ b1,
          const float* __restrict__ W2, const float* __restrict__ b2,
          const float* __restrict__ Wd, const float* __restrict__ bd,
          const float* __restrict__ wm, float* __restrict__ dense_out)
{
    __shared__ float E[RWS * PITCH];      // 133.1 KB staged embeddings
    __shared__ float exc[L1OUT];          // 8.2 KB excitements
    __shared__ float blv[4];
    __shared__ int   bli[4];
    __shared__ float topv[8];
    __shared__ int   topi[8];
    __shared__ float part[240];
    __shared__ float s1p[16][6];
    __shared__ float out2[12][14];
    __shared__ float exc2[12];

    const int b   = blockIdx.x;
    const int tid = threadIdx.x;
    const int* xb = x + b * SEQ;

    // ---- stage-1 sweep: channel-mean conv over all 2054 positions ----
    for (int chunk = 0; chunk < NCHUNK; ++chunk) {
        const int t0    = chunk * CH;
        const int chlen = (t0 + CH <= L1OUT) ? CH : (L1OUT - t0);
        const int rows  = chlen + 6;
        const int ntask = rows * NSLOT;

        // gather embedding rows -> swizzled LDS (float2 loads: rows are only 8B aligned)
        for (int task = tid; task < ntask; task += 256) {
            int j = task / NSLOT;
            int s = task - j * NSLOT;
            int g = t0 + j - 6;
            float2 lo = {0.f, 0.f}, hi = {0.f, 0.f};
            if (g >= 0 && g < SEQ) {
                const float* p = emb + (size_t)xb[g] * EMBD + s * 4;
                lo = *(const float2*)p;
                if (s < 12) hi = *(const float2*)(p + 2);
            }
            float4 v = {lo.x, lo.y, hi.x, hi.y};
            *(float4*)&E[j * PITCH + ((s ^ ((j >> 1) & 7)) << 2)] = v;
        }
        __syncthreads();

        // each thread: 2 adjacent positions, sharing 8 staged rows per slot
        const int p0 = tid * 2;
        float4 A0 = {0.f, 0.f, 0.f, 0.f}, A1 = {0.f, 0.f, 0.f, 0.f};
        for (int s = 0; s < NSLOT; ++s) {
            float4 r[8];
            #pragma unroll
            for (int m = 0; m < 8; ++m) {
                int j = p0 + m;
                r[m] = *(const float4*)&E[j * PITCH + ((s ^ ((j >> 1) & 7)) << 2)];
            }
            #pragma unroll
            for (int kw = 0; kw < 7; ++kw) {
                const float* w = wm + kw * 50 + s * 4;   // uniform -> s_load
                float w0 = w[0], w1v = w[1], w2v = w[2], w3v = w[3];
                A0.x = fmaf(r[kw].x,     w0,  A0.x);
                A0.y = fmaf(r[kw].y,     w1v, A0.y);
                A0.z = fmaf(r[kw].z,     w2v, A0.z);
                A0.w = fmaf(r[kw].w,     w3v, A0.w);
                A1.x = fmaf(r[kw + 1].x, w0,  A1.x);
                A1.y = fmaf(r[kw + 1].y, w1v, A1.y);
                A1.z = fmaf(r[kw + 1].z, w2v, A1.z);
                A1.w = fmaf(r[kw + 1].w, w3v, A1.w);
            }
        }
        if (p0 < chlen)     exc[t0 + p0]     = (A0.x + A0.y) + (A0.z + A0.w);
        if (p0 + 1 < chlen) exc[t0 + p0 + 1] = (A1.x + A1.y) + (A1.z + A1.w);
        __syncthreads();
    }

    // ---- top-8 (lax.top_k semantics: descending value, ties -> lower index) ----
    #pragma unroll 1
    for (int r = 0; r < 8; ++r) {
        float bv = -INFINITY; int bi = L1OUT;
        for (int t = tid; t < L1OUT; t += 256) {
            float v = exc[t];
            if (v > bv || (v == bv && t < bi)) { bv = v; bi = t; }
        }
        #pragma unroll
        for (int off = 32; off > 0; off >>= 1) {
            float ov = __shfl_down(bv, off, 64);
            int   oi = __shfl_down(bi, off, 64);
            if (ov > bv || (ov == bv && oi < bi)) { bv = ov; bi = oi; }
        }
        if ((tid & 63) == 0) { blv[tid >> 6] = bv; bli[tid >> 6] = bi; }
        __syncthreads();
        if (tid == 0) {
            #pragma unroll
            for (int wv = 1; wv < 4; ++wv) {
                float ov = blv[wv]; int oi = bli[wv];
                if (ov > bv || (ov == bv && oi < bi)) { bv = ov; bi = oi; }
            }
            topv[r] = bv; topi[r] = bi;
            exc[bi] = -INFINITY;
        }
        __syncthreads();
    }

    // ---- recompute full 6-channel conv1 at the 8 selected positions ----
    if (tid < 96) ((float*)s1p)[tid] = 0.f;      // zero padded stage-2 input
    if (tid < 240) {                             // (r, c, e-decile) partials
        int r = tid / 30, sub = tid - r * 30;
        int c = sub / 5,  eq  = sub - c * 5;
        int t = topi[r];
        float acc = 0.f;
        for (int kw = 0; kw < 7; ++kw) {
            int g = t + kw - 6;
            if (g >= 0 && g < SEQ) {
                const float* row = emb + (size_t)xb[g] * EMBD + eq * 10;
                const float* wp  = W1 + (kw * 50 + eq * 10) * 6 + c;
                #pragma unroll
                for (int e = 0; e < 10; ++e)
                    acc = fmaf(row[e], wp[e * 6], acc);
            }
        }
        part[tid] = acc;
    }
    __syncthreads();
    if (tid < 48) {
        int r = tid / 6, c = tid - r * 6;
        float s = b1[c];
        #pragma unroll
        for (int eq = 0; eq < 5; ++eq) s += part[r * 30 + c * 5 + eq];
        s1p[4 + r][c] = 1.0f / (1.0f + expf(-s));    // sigmoid, rows 4..11
    }
    __syncthreads();

    // ---- conv2: [16][6] -> [12][14] ----
    if (tid < 168) {
        int t = tid / 14, c = tid - t * 14;
        float acc = b2[c];
        #pragma unroll
        for (int kw = 0; kw < 5; ++kw)
            #pragma unroll
            for (int i = 0; i < 6; ++i)
                acc = fmaf(s1p[t + kw][i], W2[(kw * 6 + i) * 14 + c], acc);
        out2[t][c] = acc;
    }
    __syncthreads();
    if (tid < 12) {
        float s = 0.f;
        #pragma unroll
        for (int c = 0; c < 14; ++c) s += out2[tid][c];
        exc2[tid] = s / 14.0f;
    }
    __syncthreads();

    // ---- top-4 + mean-pool + dense (serial on thread 0; 12 candidates) ----
    if (tid == 0) {
        float ev[12];
        #pragma unroll
        for (int t = 0; t < 12; ++t) ev[t] = exc2[t];
        int sel[4];
        #pragma unroll 1
        for (int r = 0; r < 4; ++r) {
            float bv = -INFINITY; int bi = 0;
            for (int t = 0; t < 12; ++t)
                if (ev[t] > bv) { bv = ev[t]; bi = t; }   // strict > : ties -> lower idx
            sel[r] = bi; ev[bi] = -INFINITY;
        }
        float dense = bd[0];
        #pragma unroll
        for (int c = 0; c < 14; ++c) {
            float pool = 0.25f * ((out2[sel[0]][c] + out2[sel[1]][c]) +
                                  (out2[sel[2]][c] + out2[sel[3]][c]));
            dense = fmaf(pool, Wd[c], dense);
        }
        dense_out[b] = dense;
    }
}

// ---------------- finalize: mean over 256 batches + sigmoid -----------------
__global__ void __launch_bounds__(256)
finalize_kernel(const float* __restrict__ dense, float* __restrict__ out) {
    int tid = threadIdx.x;
    float v = dense[tid];
    #pragma unroll
    for (int off = 32; off > 0; off >>= 1) v += __shfl_down(v, off, 64);
    __shared__ float ws4[4];
    if ((tid & 63) == 0) ws4[tid >> 6] = v;
    __syncthreads();
    if (tid == 0) {
        float s = (ws4[0] + ws4[1]) + (ws4[2] + ws4[3]);
        float m = s * (1.0f / 256.0f);
        out[0] = 1.0f / (1.0f + expf(-m));
    }
}

extern "C" void kernel_launch(void* const* d_in, const int* in_sizes, int n_in,
                              void* d_out, int out_size, void* d_ws, size_t ws_size,
                              hipStream_t stream) {
    const int*   x   = (const int*)d_in[0];
    const float* emb = (const float*)d_in[1];
    const float* W1  = (const float*)d_in[2];
    const float* b1  = (const float*)d_in[3];
    const float* W2  = (const float*)d_in[4];
    const float* b2  = (const float*)d_in[5];
    const float* Wd  = (const float*)d_in[6];
    const float* bd  = (const float*)d_in[7];
    float* ws = (float*)d_ws;
    // ws layout: [0..352) Wm (+2 zero pad), [352..608) per-batch dense
    prep_kernel<<<1, 384, 0, stream>>>(W1, ws);
    dcnn_main<<<256, 256, 0, stream>>>(x, emb, W1, b1, W2, b2, Wd, bd,
                                       ws, ws + 352);
    finalize_kernel<<<1, 256, 0, stream>>>(ws + 352, (float*)d_out);
}

// Round 3
// 107.629 us; speedup vs baseline: 1.9449x; 1.9449x over previous
//
#include <hip/hip_runtime.h>
#include <math.h>

#define SEQ   2048
#define VOCAB 50000
#define EMBD  50
#define L1OUT 2054      // (2048+12) - 7 + 1
#define NTOK  2060      // padded-token index space i = 0..2059 (g = i-6)
#define DSTR  2064      // LDS row stride for Dv (SoA)

// ---------------- prep: Wm = mean_c W1 into ws[0..350), zeros [350..352) ----
__global__ void __launch_bounds__(384)
prep_kernel(const float* __restrict__ W1, float* __restrict__ ws) {
    int t = threadIdx.x;
    if (t < 350) {
        float s = 0.f;
        #pragma unroll
        for (int c = 0; c < 6; ++c) s += W1[t * 6 + c];
        ws[t] = s * (1.0f / 6.0f);
    } else if (t < 352) {
        ws[t] = 0.f;
    }
}

// ---------------- build_d: D[v][kw] = dot(emb[v], Wm[kw]), kw<7, pad to 8 ---
__global__ void __launch_bounds__(256)
build_d(const float* __restrict__ emb, const float* __restrict__ wm,
        float* __restrict__ D) {
    int v = blockIdx.x * 256 + threadIdx.x;
    if (v >= VOCAB) return;
    const float2* row = (const float2*)(emb + (size_t)v * EMBD);
    float d[7] = {0.f, 0.f, 0.f, 0.f, 0.f, 0.f, 0.f};
    for (int e = 0; e < 25; ++e) {
        float2 r = row[e];
        #pragma unroll
        for (int kw = 0; kw < 7; ++kw)
            d[kw] = fmaf(r.y, wm[kw * 50 + 2 * e + 1],
                    fmaf(r.x, wm[kw * 50 + 2 * e], d[kw]));
    }
    float4* out = (float4*)(D + (size_t)v * 8);
    out[0] = make_float4(d[0], d[1], d[2], d[3]);
    out[1] = make_float4(d[4], d[5], d[6], 0.f);
}

// ---------------- main: one block (512 thr) per batch -----------------------
template<int USE_D>
__global__ void __launch_bounds__(512, 1)
dcnn_main(const int* __restrict__ x, const float* __restrict__ emb,
          const float* __restrict__ W1, const float* __restrict__ b1,
          const float* __restrict__ W2, const float* __restrict__ b2,
          const float* __restrict__ Wd, const float* __restrict__ bd,
          const float* __restrict__ Dtab, const float* __restrict__ wm,
          float* __restrict__ dense_out)
{
    __shared__ float Dv[7][DSTR];         // 57.8 KB SoA per-token dot values
    __shared__ float exc[L1OUT];          // 8.2 KB excitements
    __shared__ float blv[8];
    __shared__ int   bli[8];
    __shared__ int   topi[8];
    __shared__ float part[240];
    __shared__ float s1p[16][6];
    __shared__ float out2[12][14];
    __shared__ float exc2[12];

    const int b   = blockIdx.x;
    const int tid = threadIdx.x;
    const int* xb = x + b * SEQ;

    // ---- gather per-token D rows into SoA LDS (L2-resident 1.6 MB table) ----
    for (int i = tid; i < NTOK; i += 512) {
        int g = i - 6;
        float d0 = 0.f, d1 = 0.f, d2 = 0.f, d3 = 0.f,
              d4 = 0.f, d5 = 0.f, d6 = 0.f;
        if (g >= 0 && g < SEQ) {
            int tok = xb[g];
            if (USE_D) {
                const float4* dp = (const float4*)(Dtab + (size_t)tok * 8);
                float4 lo = dp[0], hi = dp[1];
                d0 = lo.x; d1 = lo.y; d2 = lo.z; d3 = lo.w;
                d4 = hi.x; d5 = hi.y; d6 = hi.z;
            } else {
                const float2* row = (const float2*)(emb + (size_t)tok * EMBD);
                float dd[7] = {0.f, 0.f, 0.f, 0.f, 0.f, 0.f, 0.f};
                for (int e = 0; e < 25; ++e) {
                    float2 r = row[e];
                    #pragma unroll
                    for (int kw = 0; kw < 7; ++kw)
                        dd[kw] = fmaf(r.y, wm[kw * 50 + 2 * e + 1],
                                 fmaf(r.x, wm[kw * 50 + 2 * e], dd[kw]));
                }
                d0 = dd[0]; d1 = dd[1]; d2 = dd[2]; d3 = dd[3];
                d4 = dd[4]; d5 = dd[5]; d6 = dd[6];
            }
        }
        Dv[0][i] = d0; Dv[1][i] = d1; Dv[2][i] = d2; Dv[3][i] = d3;
        Dv[4][i] = d4; Dv[5][i] = d5; Dv[6][i] = d6;
    }
    __syncthreads();

    // ---- excitements: 7-tap stencil over SoA rows (conflict-free b32) ----
    for (int t = tid; t < L1OUT; t += 512) {
        float s = ((Dv[0][t] + Dv[1][t + 1]) + (Dv[2][t + 2] + Dv[3][t + 3]))
                + ((Dv[4][t + 4] + Dv[5][t + 5]) + Dv[6][t + 6]);
        exc[t] = s;
    }
    __syncthreads();

    // ---- top-8 (lax.top_k: descending value, ties -> lower index) ----
    #pragma unroll 1
    for (int r = 0; r < 8; ++r) {
        float bv = -INFINITY; int bi = L1OUT;
        for (int t = tid; t < L1OUT; t += 512) {
            float v = exc[t];
            if (v > bv || (v == bv && t < bi)) { bv = v; bi = t; }
        }
        #pragma unroll
        for (int off = 32; off > 0; off >>= 1) {
            float ov = __shfl_down(bv, off, 64);
            int   oi = __shfl_down(bi, off, 64);
            if (ov > bv || (ov == bv && oi < bi)) { bv = ov; bi = oi; }
        }
        if ((tid & 63) == 0) { blv[tid >> 6] = bv; bli[tid >> 6] = bi; }
        __syncthreads();
        if (tid == 0) {
            #pragma unroll
            for (int w = 1; w < 8; ++w) {
                float ov = blv[w]; int oi = bli[w];
                if (ov > bv || (ov == bv && oi < bi)) { bv = ov; bi = oi; }
            }
            topi[r] = bi;
            exc[bi] = -INFINITY;
        }
        __syncthreads();
    }

    // ---- recompute full 6-channel conv1 at the 8 selected positions ----
    if (tid < 96) ((float*)s1p)[tid] = 0.f;      // zero padded stage-2 input
    if (tid < 240) {                             // (r, c, e-decile) partials
        int r = tid / 30, sub = tid - r * 30;
        int c = sub / 5,  eq  = sub - c * 5;
        int t = topi[r];
        float acc = 0.f;
        for (int kw = 0; kw < 7; ++kw) {
            int g = t + kw - 6;
            if (g >= 0 && g < SEQ) {
                const float* row = emb + (size_t)xb[g] * EMBD + eq * 10;
                const float* wp  = W1 + (kw * 50 + eq * 10) * 6 + c;
                #pragma unroll
                for (int e = 0; e < 10; ++e)
                    acc = fmaf(row[e], wp[e * 6], acc);
            }
        }
        part[tid] = acc;
    }
    __syncthreads();
    if (tid < 48) {
        int r = tid / 6, c = tid - r * 6;
        float s = b1[c];
        #pragma unroll
        for (int eq = 0; eq < 5; ++eq) s += part[r * 30 + c * 5 + eq];
        s1p[4 + r][c] = 1.0f / (1.0f + expf(-s));    // sigmoid, rows 4..11
    }
    __syncthreads();

    // ---- conv2: [16][6] -> [12][14] ----
    if (tid < 168) {
        int t = tid / 14, c = tid - t * 14;
        float acc = b2[c];
        #pragma unroll
        for (int kw = 0; kw < 5; ++kw)
            #pragma unroll
            for (int i = 0; i < 6; ++i)
                acc = fmaf(s1p[t + kw][i], W2[(kw * 6 + i) * 14 + c], acc);
        out2[t][c] = acc;
    }
    __syncthreads();
    if (tid < 12) {
        float s = 0.f;
        #pragma unroll
        for (int c = 0; c < 14; ++c) s += out2[tid][c];
        exc2[tid] = s / 14.0f;
    }
    __syncthreads();

    // ---- top-4 + mean-pool + dense (serial on thread 0; 12 candidates) ----
    if (tid == 0) {
        float ev[12];
        #pragma unroll
        for (int t = 0; t < 12; ++t) ev[t] = exc2[t];
        int sel[4];
        #pragma unroll 1
        for (int r = 0; r < 4; ++r) {
            float bv = -INFINITY; int bi = 0;
            for (int t = 0; t < 12; ++t)
                if (ev[t] > bv) { bv = ev[t]; bi = t; }   // strict > : ties -> lower idx
            sel[r] = bi; ev[bi] = -INFINITY;
        }
        float dense = bd[0];
        #pragma unroll
        for (int c = 0; c < 14; ++c) {
            float pool = 0.25f * ((out2[sel[0]][c] + out2[sel[1]][c]) +
                                  (out2[sel[2]][c] + out2[sel[3]][c]));
            dense = fmaf(pool, Wd[c], dense);
        }
        dense_out[b] = dense;
    }
}

// ---------------- finalize: mean over 256 batches + sigmoid -----------------
__global__ void __launch_bounds__(256)
finalize_kernel(const float* __restrict__ dense, float* __restrict__ out) {
    int tid = threadIdx.x;
    float v = dense[tid];
    #pragma unroll
    for (int off = 32; off > 0; off >>= 1) v += __shfl_down(v, off, 64);
    __shared__ float ws4[4];
    if ((tid & 63) == 0) ws4[tid >> 6] = v;
    __syncthreads();
    if (tid == 0) {
        float s = (ws4[0] + ws4[1]) + (ws4[2] + ws4[3]);
        float m = s * (1.0f / 256.0f);
        out[0] = 1.0f / (1.0f + expf(-m));
    }
}

extern "C" void kernel_launch(void* const* d_in, const int* in_sizes, int n_in,
                              void* d_out, int out_size, void* d_ws, size_t ws_size,
                              hipStream_t stream) {
    const int*   x   = (const int*)d_in[0];
    const float* emb = (const float*)d_in[1];
    const float* W1  = (const float*)d_in[2];
    const float* b1  = (const float*)d_in[3];
    const float* W2  = (const float*)d_in[4];
    const float* b2  = (const float*)d_in[5];
    const float* Wd  = (const float*)d_in[6];
    const float* bd  = (const float*)d_in[7];
    float* ws = (float*)d_ws;

    // D-path ws layout: [0..352) Wm, [384..400384) D (16B aligned), then dense
    const size_t needD = (size_t)(384 + VOCAB * 8 + 256) * sizeof(float);

    prep_kernel<<<1, 384, 0, stream>>>(W1, ws);
    if (ws_size >= needD) {
        float* D     = ws + 384;
        float* dense = ws + 384 + VOCAB * 8;
        build_d<<<(VOCAB + 255) / 256, 256, 0, stream>>>(emb, ws, D);
        dcnn_main<1><<<256, 512, 0, stream>>>(x, emb, W1, b1, W2, b2, Wd, bd,
                                              D, ws, dense);
        finalize_kernel<<<1, 256, 0, stream>>>(dense, (float*)d_out);
    } else {
        float* dense = ws + 352;
        dcnn_main<0><<<256, 512, 0, stream>>>(x, emb, W1, b1, W2, b2, Wd, bd,
                                              ws, ws, dense);
        finalize_kernel<<<1, 256, 0, stream>>>(dense, (float*)d_out);
    }
}